// Round 4
// baseline (1089.214 us; speedup 1.0000x reference)
//
#include <hip/hip_runtime.h>

// Infusion: local dilated-window attention, float32 end-to-end.
// N=8, C=256 (8 heads x 32 ch), H=W=128, ksize=5, dilation=3, pad=6, 25 taps.
//
// V5: V3 skeleton (proven 201us, no spills) with three deltas:
//  - 1-channel double-buffered periods: stg = 3 f4 (12 regs, was 24), LDS =
//    2 x 20x144 x 4B = 23 KB (was 46 KB). One barrier per channel; prefetch
//    for channel c+2 is issued at the top of period c+1's compute and drained
//    by that period's ending barrier (full-period slack, as V3).
//  - Aligned ds_read_b128 inner loop (V4's one good part): per row, 5 f4
//    covering cols [xs, xs+19]; LSTR=144 keeps rows 16B-aligned; staging
//    writes are single f4 (ds_write_b128), consecutive lanes -> consecutive
//    16B. V3's b64-at-16B-stride was a 4-way intra-half-wave conflict.
//  - __launch_bounds__(256,3): peak live state ~155 regs (s[100]+stg[12]+
//    q[8]+window[20]+misc) fits the ~170 cap -> 3 waves/SIMD, 3 blocks/CU
//    (V3/V4 ran at 2 blocks/CU; stalls were naked at 2 waves/SIMD).
//    V4's lesson: state > cap => scratch spill => 1.5 GB extra HBM traffic.
//    Check: WRITE_SIZE must be exactly 131072 KB.
//  - Zero-padded borders + OOB rows zeroed once, never rewritten: padding
//    semantics with zero masking in the inner loop.

#define Hh 128
#define Ww 128
#define HD 32
#define TAPS 25
#define LROWS 20
#define LSTR 144           // floats; col = x + 8; interior cols 8..135
#define CHW (LROWS * LSTR) // 2880 floats per channel tile

typedef float4 f4;

__global__ __launch_bounds__(256, 3) void infusion_kernel(
    const float* __restrict__ Vt,
    const float* __restrict__ Kt,
    const float* __restrict__ Qt,
    float* __restrict__ Ot)
{
    __shared__ alignas(16) float lbuf[2][CHW];  // 23040 B

    const int tid = threadIdx.x;
    const int tx  = tid & 31;   // x-group (4 pixels each)
    const int ty  = tid >> 5;   // 0..7
    const int Rb  = blockIdx.x * 8;
    const int row = Rb + ty;
    const int nh  = blockIdx.y; // n*8 + head
    const int xs  = tx << 2;

    const size_t plane = (size_t)Hh * Ww;
    const size_t cbase = (size_t)nh * HD * plane;
    const int qoff = row * Ww + xs;

    // staging map: 640 chunks of 16B (20 rows x 32 xchunks) per channel.
    // thread t handles chunks t, t+256, t+512 (t<128): coalesced in global,
    // sequential-contiguous in LDS.
    bool sgv[3]; int sgo[3]; float* wp[3];
#pragma unroll
    for (int k = 0; k < 3; ++k) {
        const int q  = tid + (k << 8);
        const int lr = q >> 5, xc = q & 31;
        const int r  = Rb + lr - 6;
        const bool ok = (q < 640) && (r >= 0) && (r < Hh);
        sgv[k] = ok;
        sgo[k] = ok ? (r * Ww + (xc << 2)) : 0;
        wp[k]  = &lbuf[0][0] + (lr < LROWS ? lr : 0) * LSTR + 8 + (xc << 2);
    }

    // zero both buffers once; borders and OOB rows stay zero forever
    for (int i = tid; i < 2 * CHW; i += 256) (&lbuf[0][0])[i] = 0.f;

    const float* Kb = Kt + cbase;
    const float* Qb = Qt + cbase;
    const float* Vb = Vt + cbase;
    float*       Ob = Ot + cbase;
    const float* lb0 = &lbuf[0][0] + ty * LSTR + xs;  // read base, buf 0

    f4 stg[3];
    auto loadg = [&](const float* B, int c) {   // issue channel c staging loads
        const float* p = B + (size_t)c * plane;
        stg[0] = *(const f4*)(p + sgo[0]);
        stg[1] = *(const f4*)(p + sgo[1]);
        stg[2] = *(const f4*)(p + sgo[2]);
    };
    auto writeg = [&](int bi) {                 // commit stg to buffer bi
#pragma unroll
        for (int k = 0; k < 3; ++k)
            if (sgv[k]) *(f4*)(wp[k] + bi * CHW) = stg[k];
    };

    float s[4][TAPS];
#pragma unroll
    for (int a = 0; a < 4; ++a)
#pragma unroll
        for (int p = 0; p < TAPS; ++p) s[a][p] = 0.f;

    // ---------------- phase 1: scores = K . Q over 32 channels ----------------
    {
        loadg(Kb, 0);
        f4 qc = *(const f4*)(Qb + qoff);
        __syncthreads();            // zero-init visible; drains ch0 loads
        writeg(0);
        loadg(Kb, 1);
        __syncthreads();            // buf0 visible; drains ch1 loads
#pragma unroll 1
        for (int c = 0; c < HD; ++c) {
            if (c < HD - 1) writeg((c + 1) & 1);   // stg = ch c+1 (complete)
            if (c < HD - 2) loadg(Kb, c + 2);      // in flight across compute
            f4 qn;
            if (c < HD - 1)                         // q for ch c+1, in flight
                qn = *(const f4*)(Qb + (size_t)(c + 1) * plane + qoff);
            const float* lb = lb0 + (c & 1) * CHW;
#pragma unroll
            for (int fy = 0; fy < 5; ++fy) {
                const float* rp = lb + fy * (3 * LSTR);
                const f4 w0 = *(const f4*)(rp + 0);
                const f4 w1 = *(const f4*)(rp + 4);
                const f4 w2 = *(const f4*)(rp + 8);
                const f4 w3 = *(const f4*)(rp + 12);
                const f4 w4 = *(const f4*)(rp + 16);
                const float v[20] = { w0.x, w0.y, w0.z, w0.w,
                                      w1.x, w1.y, w1.z, w1.w,
                                      w2.x, w2.y, w2.z, w2.w,
                                      w3.x, w3.y, w3.z, w3.w,
                                      w4.x, w4.y, w4.z, w4.w };
#pragma unroll
                for (int fx = 0; fx < 5; ++fx) {
                    const int p = fy * 5 + fx;
                    s[0][p] = fmaf(v[2 + 3 * fx], qc.x, s[0][p]);
                    s[1][p] = fmaf(v[3 + 3 * fx], qc.y, s[1][p]);
                    s[2][p] = fmaf(v[4 + 3 * fx], qc.z, s[2][p]);
                    s[3][p] = fmaf(v[5 + 3 * fx], qc.w, s[3][p]);
                }
            }
            if (c < HD - 1) __syncthreads();  // drains this period's prefetch
            qc = qn;
        }
    }

    // ---------------- phase 2 prologue: V ch0 in flight under softmax --------
    loadg(Vb, 0);

    // ---------------- softmax over the 25 taps ----------------
#pragma unroll
    for (int a = 0; a < 4; ++a) {
        float m = s[a][0];
#pragma unroll
        for (int p = 1; p < TAPS; ++p) m = fmaxf(m, s[a][p]);
        float sum = 0.f;
#pragma unroll
        for (int p = 0; p < TAPS; ++p) { float e = __expf(s[a][p] - m); s[a][p] = e; sum += e; }
        const float rs = 1.0f / sum;
#pragma unroll
        for (int p = 0; p < TAPS; ++p) s[a][p] *= rs;
    }

    // ---------------- phase 2: out = sum_p att[p] * V_shift[p] ----------------
    {
        writeg(0);                  // waits on the softmax-covered loads
        loadg(Vb, 1);
        __syncthreads();            // buf0 visible; all waves past phase-1 reads
#pragma unroll 1
        for (int c = 0; c < HD; ++c) {
            if (c < HD - 1) writeg((c + 1) & 1);
            if (c < HD - 2) loadg(Vb, c + 2);
            const float* lb = lb0 + (c & 1) * CHW;
            float a0 = 0.f, a1 = 0.f, a2 = 0.f, a3 = 0.f;
#pragma unroll
            for (int fy = 0; fy < 5; ++fy) {
                const float* rp = lb + fy * (3 * LSTR);
                const f4 w0 = *(const f4*)(rp + 0);
                const f4 w1 = *(const f4*)(rp + 4);
                const f4 w2 = *(const f4*)(rp + 8);
                const f4 w3 = *(const f4*)(rp + 12);
                const f4 w4 = *(const f4*)(rp + 16);
                const float v[20] = { w0.x, w0.y, w0.z, w0.w,
                                      w1.x, w1.y, w1.z, w1.w,
                                      w2.x, w2.y, w2.z, w2.w,
                                      w3.x, w3.y, w3.z, w3.w,
                                      w4.x, w4.y, w4.z, w4.w };
#pragma unroll
                for (int fx = 0; fx < 5; ++fx) {
                    const int p = fy * 5 + fx;
                    a0 = fmaf(v[2 + 3 * fx], s[0][p], a0);
                    a1 = fmaf(v[3 + 3 * fx], s[1][p], a1);
                    a2 = fmaf(v[4 + 3 * fx], s[2][p], a2);
                    a3 = fmaf(v[5 + 3 * fx], s[3][p], a3);
                }
            }
            *(f4*)(Ob + (size_t)c * plane + qoff) = make_float4(a0, a1, a2, a3);
            if (c < HD - 1) __syncthreads();
        }
    }
}

extern "C" void kernel_launch(void* const* d_in, const int* in_sizes, int n_in,
                              void* d_out, int out_size, void* d_ws, size_t ws_size,
                              hipStream_t stream) {
    const float* V = (const float*)d_in[0];
    const float* K = (const float*)d_in[1];
    const float* Q = (const float*)d_in[2];
    // d_in[3] = ksize (5), d_in[4] = dilation (3): fixed by setup_inputs.
    float* O = (float*)d_out;

    const int N = in_sizes[0] / (256 * Hh * Ww);  // = 8
    dim3 grid(Hh / 8, N * 8);
    dim3 block(256);
    infusion_kernel<<<grid, block, 0, stream>>>(V, K, Q, O);
}

// Round 5
// 674.860 us; speedup vs baseline: 1.6140x; 1.6140x over previous
//
#include <hip/hip_runtime.h>

// Infusion: local dilated-window attention, float32 end-to-end.
// N=8, C=256 (8 heads x 32 ch), H=W=128, ksize=5, dilation=3, pad=6, 25 taps.
//
// V6: 2 pixels/thread (was 4) to halve the score-register state.
//  Evidence from V1-V5: hipcc splits the gfx950 unified reg file ~50/50
//  arch/accum under __launch_bounds__; arch demand > cap/2 => scratch spill
//  (V4: 128+spill, V5: 84+spill). Only (256,2) was ever spill-free (V3: 120).
//  V3's wall (201us) = stalls at 2 waves/SIMD, nothing saturated (VALU 31%,
//  HBM 33%, LDS data-path ~1%). So: shrink state -> s[2][25]=50 regs,
//  target arch <=~120 at (256,2) -> 4 waves/SIMD, 4 independent blocks/CU
//  (LDS 36.9KB). Independent blocks overlap each other's barrier drains.
//
//  Mapping: block = 128x4 tile; wave = one full row (64 thr x 2px) -> row
//  bounds are wave-uniform, no divergence. LDS tile [2buf][2ch][16][144],
//  col = x+8: staging ds_write_b128 aligned (col 8+4*xc), window reads are
//  8B-aligned float2 (cols 2tx+2 .. 2tx+15), pairable into ds_read2_b64.
//  Zero borders + OOB rows zeroed once -> padding semantics, no masking.
//  Pipeline per 2-ch period (as V3): writeg -> loadg(+2) -> compute -> sync.

#define Hh 128
#define Ww 128
#define HD 32
#define TAPS 25
#define TROWS 4            // output rows per block
#define LROWS 16           // TROWS + 2*pad
#define LSTR 144           // floats; col = x + 8; data cols 8..135
#define CHW (LROWS * LSTR) // 2304 floats per channel tile
#define PERW (2 * CHW)     // 4608 floats per 2-channel buffer

typedef float4 f4;
typedef float2 f2;

__global__ __launch_bounds__(256, 2) void infusion_kernel(
    const float* __restrict__ Vt,
    const float* __restrict__ Kt,
    const float* __restrict__ Qt,
    float* __restrict__ Ot)
{
    __shared__ alignas(16) float lbuf[2][PERW];  // 36864 B

    const int tid = threadIdx.x;
    const int tx  = tid & 63;   // x-pair index (2 px each)
    const int ty  = tid >> 6;   // 0..3
    const int Rb  = blockIdx.x * TROWS;
    const int row = Rb + ty;
    const int nh  = blockIdx.y; // n*8 + head
    const int x0  = tx << 1;

    const size_t plane = (size_t)Hh * Ww;
    const size_t cbase = (size_t)nh * HD * plane;
    const int qoff = row * Ww + x0;

    // staging map: 512 chunks of 16B (16 rows x 32 xchunks) per channel.
    // thread t handles chunks t, t+256: coalesced in global and LDS.
    bool sgv[2]; int sgo[2]; float* wp[2];
#pragma unroll
    for (int k = 0; k < 2; ++k) {
        const int q  = tid + (k << 8);
        const int lr = q >> 5, xc = q & 31;
        const int r  = Rb + lr - 6;
        const bool ok = (r >= 0) && (r < Hh);
        sgv[k] = ok;
        sgo[k] = ok ? (r * Ww + (xc << 2)) : 0;
        wp[k]  = &lbuf[0][0] + lr * LSTR + 8 + (xc << 2);
    }

    // zero both buffers once; borders and OOB rows stay zero forever
    for (int i = tid; i < 2 * PERW; i += 256) (&lbuf[0][0])[i] = 0.f;

    const float* Kb = Kt + cbase;
    const float* Qb = Qt + cbase;
    const float* Vb = Vt + cbase;
    float*       Ob = Ot + cbase;
    // read base: window start col = x0 + 2 (= x0-6 data col)
    const float* lb0 = &lbuf[0][0] + ty * LSTR + x0 + 2;

    f4 stg[4];  // 2 channels x 2 chunks, in flight across compute
    auto loadg = [&](const float* B, int c0) {   // issue channels c0, c0+1
        const float* p0 = B + (size_t)c0 * plane;
        const float* p1 = p0 + plane;
        stg[0] = *(const f4*)(p0 + sgo[0]);
        stg[1] = *(const f4*)(p0 + sgo[1]);
        stg[2] = *(const f4*)(p1 + sgo[0]);
        stg[3] = *(const f4*)(p1 + sgo[1]);
    };
    auto writeg = [&](int bi) {                  // commit stg to buffer bi
#pragma unroll
        for (int cc = 0; cc < 2; ++cc)
#pragma unroll
            for (int k = 0; k < 2; ++k)
                if (sgv[k]) *(f4*)(wp[k] + bi * PERW + cc * CHW) = stg[cc * 2 + k];
    };

    float s0[TAPS], s1[TAPS];
#pragma unroll
    for (int p = 0; p < TAPS; ++p) { s0[p] = 0.f; s1[p] = 0.f; }

    // ---------------- phase 1: scores = K . Q over 32 channels ----------------
    {
        loadg(Kb, 0);
        f2 qc0 = *(const f2*)(Qb + qoff);
        f2 qc1 = *(const f2*)(Qb + plane + qoff);
        __syncthreads();            // zero-init visible; drains ch0/1 loads
        writeg(0);
        loadg(Kb, 2);
        __syncthreads();            // buf0 visible
#pragma unroll 1
        for (int it = 0; it < 16; ++it) {
            if (it < 15) writeg((it + 1) & 1);   // stg = chans 2it+2,+3 (complete)
            if (it < 14) loadg(Kb, 2 * it + 4);  // in flight across compute
            f2 qn0, qn1;
            if (it < 15) {
                qn0 = *(const f2*)(Qb + (size_t)(2 * it + 2) * plane + qoff);
                qn1 = *(const f2*)(Qb + (size_t)(2 * it + 3) * plane + qoff);
            }
            const float* lb = lb0 + (it & 1) * PERW;
#pragma unroll
            for (int cc = 0; cc < 2; ++cc) {
                const f2 q = cc ? qc1 : qc0;
#pragma unroll
                for (int fy = 0; fy < 5; ++fy) {
                    const f2* rp = (const f2*)(lb + cc * CHW + fy * (3 * LSTR));
                    const f2 w0 = rp[0], w1 = rp[1], w2 = rp[2], w3 = rp[3];
                    const f2 w4 = rp[4], w5 = rp[5], w6 = rp[6];
                    const int p = fy * 5;
                    s0[p + 0] = fmaf(w0.x, q.x, s0[p + 0]);
                    s0[p + 1] = fmaf(w1.y, q.x, s0[p + 1]);
                    s0[p + 2] = fmaf(w3.x, q.x, s0[p + 2]);
                    s0[p + 3] = fmaf(w4.y, q.x, s0[p + 3]);
                    s0[p + 4] = fmaf(w6.x, q.x, s0[p + 4]);
                    s1[p + 0] = fmaf(w0.y, q.y, s1[p + 0]);
                    s1[p + 1] = fmaf(w2.x, q.y, s1[p + 1]);
                    s1[p + 2] = fmaf(w3.y, q.y, s1[p + 2]);
                    s1[p + 3] = fmaf(w5.x, q.y, s1[p + 3]);
                    s1[p + 4] = fmaf(w6.y, q.y, s1[p + 4]);
                }
            }
            if (it < 15) __syncthreads();  // drains this period's prefetch
            qc0 = qn0; qc1 = qn1;
        }
    }

    // ---------------- phase 2 prologue: V ch0/1 in flight under softmax ------
    loadg(Vb, 0);

    // ---------------- softmax over the 25 taps ----------------
    {
        float m0 = s0[0], m1 = s1[0];
#pragma unroll
        for (int p = 1; p < TAPS; ++p) { m0 = fmaxf(m0, s0[p]); m1 = fmaxf(m1, s1[p]); }
        float t0 = 0.f, t1 = 0.f;
#pragma unroll
        for (int p = 0; p < TAPS; ++p) {
            float e0 = __expf(s0[p] - m0); s0[p] = e0; t0 += e0;
            float e1 = __expf(s1[p] - m1); s1[p] = e1; t1 += e1;
        }
        const float r0 = 1.0f / t0, r1 = 1.0f / t1;
#pragma unroll
        for (int p = 0; p < TAPS; ++p) { s0[p] *= r0; s1[p] *= r1; }
    }

    // ---------------- phase 2: out = sum_p att[p] * V_shift[p] ----------------
    {
        writeg(0);                  // waits on the softmax-covered loads
        loadg(Vb, 2);
        __syncthreads();            // buf0 visible; all waves past phase-1 reads
        float* op = Ob + qoff;
#pragma unroll 1
        for (int it = 0; it < 16; ++it) {
            if (it < 15) writeg((it + 1) & 1);
            if (it < 14) loadg(Vb, 2 * it + 4);
            const float* lb = lb0 + (it & 1) * PERW;
#pragma unroll
            for (int cc = 0; cc < 2; ++cc) {
                float a0 = 0.f, a1 = 0.f;
#pragma unroll
                for (int fy = 0; fy < 5; ++fy) {
                    const f2* rp = (const f2*)(lb + cc * CHW + fy * (3 * LSTR));
                    const f2 w0 = rp[0], w1 = rp[1], w2 = rp[2], w3 = rp[3];
                    const f2 w4 = rp[4], w5 = rp[5], w6 = rp[6];
                    const int p = fy * 5;
                    a0 = fmaf(w0.x, s0[p + 0], a0);
                    a0 = fmaf(w1.y, s0[p + 1], a0);
                    a0 = fmaf(w3.x, s0[p + 2], a0);
                    a0 = fmaf(w4.y, s0[p + 3], a0);
                    a0 = fmaf(w6.x, s0[p + 4], a0);
                    a1 = fmaf(w0.y, s1[p + 0], a1);
                    a1 = fmaf(w2.x, s1[p + 1], a1);
                    a1 = fmaf(w3.y, s1[p + 2], a1);
                    a1 = fmaf(w5.x, s1[p + 3], a1);
                    a1 = fmaf(w6.y, s1[p + 4], a1);
                }
                *(f2*)(op + (size_t)(2 * it + cc) * plane) = make_float2(a0, a1);
            }
            if (it < 15) __syncthreads();
        }
    }
}

extern "C" void kernel_launch(void* const* d_in, const int* in_sizes, int n_in,
                              void* d_out, int out_size, void* d_ws, size_t ws_size,
                              hipStream_t stream) {
    const float* V = (const float*)d_in[0];
    const float* K = (const float*)d_in[1];
    const float* Q = (const float*)d_in[2];
    // d_in[3] = ksize (5), d_in[4] = dilation (3): fixed by setup_inputs.
    float* O = (float*)d_out;

    const int N = in_sizes[0] / (256 * Hh * Ww);  // = 8
    dim3 grid(Hh / TROWS, N * 8);
    dim3 block(256);
    infusion_kernel<<<grid, block, 0, stream>>>(V, K, Q, O);
}

// Round 6
// 624.637 us; speedup vs baseline: 1.7438x; 1.0804x over previous
//
#include <hip/hip_runtime.h>

// Infusion: local dilated-window attention, float32 end-to-end.
// N=8, C=256 (8 heads x 32 ch), H=W=128, ksize=5, dilation=3, pad=6, 25 taps.
//
// V7: V3 skeleton (201us champion; 8-row tile, 4px/thread, 2-ch double-
// buffered periods, Q pipelined one period ahead, (256,2)) with ONE delta:
// the per-(fy) window read is 5 aligned ds_read_b128 instead of 8 b64.
//  - Cost model (V3 counters): V3's wall IS the LDS read pipe: 41k b64
//    wave-instrs/CU at ~8-10 cyc (4-way conflict at 16B lane stride) =
//    330-410k cyc vs the 483k wall. 5xb128 moves the same 16-word window
//    at the conflict-free-ish 8-pass floor -> ~310k cyc/CU.
//  - V4 already proved the b128 pattern but spilled (templates + v[20]
//    arrays). Here: single loop body, named scalar components, no arrays.
//  - LSTR=144 (rows 16B-aligned): staging chunk = one ds_write_b128.
//  - V6 lesson: 2.1e7 conflict count on conflict-free reads => the counter
//    is mostly structural multi-pass; don't chase it below ~6/instr.
//  - Zero-padded borders + OOB rows zeroed once, never rewritten ->
//    padding semantics with zero masking in the inner loop.
// Spill tripwire: WRITE_SIZE must be exactly 131072 KB.

#define Hh 128
#define Ww 128
#define HD 32
#define TAPS 25
#define LROWS 20
#define LSTR 144           // floats; padded col = x + 8; data cols 8..135
#define CHW (LROWS * LSTR) // 2880 floats per channel tile
#define BUFW (2 * CHW)     // 5760 floats per 2-channel buffer

typedef float4 f4;

__global__ __launch_bounds__(256, 2) void infusion_kernel(
    const float* __restrict__ Vt,
    const float* __restrict__ Kt,
    const float* __restrict__ Qt,
    float* __restrict__ Ot)
{
    __shared__ alignas(16) float lbuf[2][BUFW];  // 46080 B

    const int tid = threadIdx.x;
    const int tx  = tid & 31;   // x-group (4 pixels each)
    const int ty  = tid >> 5;   // 0..7
    const int Rb  = blockIdx.x * 8;
    const int row = Rb + ty;
    const int nh  = blockIdx.y; // n*8 + head
    const int xs  = tx << 2;

    const size_t plane = (size_t)Hh * Ww;
    const size_t cbase = (size_t)nh * HD * plane;
    const int qoff = row * Ww + xs;

    // staging map: 640 chunks of 16B (20 rows x 32 xchunks) per channel.
    // thread t handles chunks t, t+256, t+512 (t<128): coalesced in global,
    // 16B-aligned ds_write_b128 in LDS.
    bool sgv[3]; int sgo[3]; float* wp[3];
#pragma unroll
    for (int k = 0; k < 3; ++k) {
        const int q  = tid + (k << 8);
        const int lr = q >> 5, xc = q & 31;
        const int r  = Rb + lr - 6;
        const bool ok = (q < 640) && (r >= 0) && (r < Hh);
        sgv[k] = ok;
        sgo[k] = ok ? (r * Ww + (xc << 2)) : 0;
        wp[k]  = &lbuf[0][0] + (lr < LROWS ? lr : 0) * LSTR + 8 + (xc << 2);
    }

    // zero both buffers once; borders and OOB rows stay zero forever
    for (int i = tid; i < 2 * BUFW; i += 256) (&lbuf[0][0])[i] = 0.f;

    const float* Kb = Kt + cbase;
    const float* Qb = Qt + cbase;
    const float* Vb = Vt + cbase;
    float*       Ob = Ot + cbase;
    // read base at padded col xs: component i of the 20-word window = padded
    // col xs+i; pixel a, tap fx uses v_{a+3fx+2}. 16B-aligned (576*ty + 16*tx).
    const float* lb0 = &lbuf[0][0] + ty * LSTR + xs;

    f4 stg[6];  // 2 channels x 3 chunks, in flight across compute
    auto loadg = [&](const float* B, int g) {  // issue channels g, g+1
        const float* p0 = B + (size_t)g * plane;
        const float* p1 = p0 + plane;
        stg[0] = *(const f4*)(p0 + sgo[0]);
        stg[1] = *(const f4*)(p0 + sgo[1]);
        stg[2] = *(const f4*)(p0 + sgo[2]);
        stg[3] = *(const f4*)(p1 + sgo[0]);
        stg[4] = *(const f4*)(p1 + sgo[1]);
        stg[5] = *(const f4*)(p1 + sgo[2]);
    };
    auto writeg = [&](int bi) {                // commit stg to buffer bi
#pragma unroll
        for (int cc = 0; cc < 2; ++cc)
#pragma unroll
            for (int k = 0; k < 3; ++k)
                if (sgv[k]) *(f4*)(wp[k] + bi * BUFW + cc * CHW) = stg[cc * 3 + k];
    };

    float s[4][TAPS];
#pragma unroll
    for (int a = 0; a < 4; ++a)
#pragma unroll
        for (int p = 0; p < TAPS; ++p) s[a][p] = 0.f;

    // ---------------- phase 1: scores = K . Q over 32 channels ----------------
    {
        loadg(Kb, 0);
        f4 qc0 = *(const f4*)(Qb + qoff);
        f4 qc1 = *(const f4*)(Qb + plane + qoff);
        f4 qn0 = qc0, qn1 = qc1;
        __syncthreads();            // zero-init visible; drains ch0/1 loads
        writeg(0);
        loadg(Kb, 2);
        __syncthreads();            // buf0 visible
#pragma unroll 1
        for (int it = 0; it < 16; ++it) {
            if (it < 15) writeg((it + 1) & 1);   // stg = chans 2it+2,+3 (complete)
            if (it < 14) loadg(Kb, 2 * it + 4);  // in flight across compute
            if (it < 15) {
                qn0 = *(const f4*)(Qb + (size_t)(2 * it + 2) * plane + qoff);
                qn1 = *(const f4*)(Qb + (size_t)(2 * it + 3) * plane + qoff);
            }
            const float* lb = lb0 + (it & 1) * BUFW;
#pragma unroll
            for (int cc = 0; cc < 2; ++cc) {
                const f4 q = cc ? qc1 : qc0;
#pragma unroll
                for (int fy = 0; fy < 5; ++fy) {
                    const float* rp = lb + cc * CHW + fy * (3 * LSTR);
                    const f4 w0 = *(const f4*)(rp + 0);
                    const f4 w1 = *(const f4*)(rp + 4);
                    const f4 w2 = *(const f4*)(rp + 8);
                    const f4 w3 = *(const f4*)(rp + 12);
                    const f4 w4 = *(const f4*)(rp + 16);
                    const float v2 = w0.z, v3 = w0.w, v4 = w1.x, v5 = w1.y;
                    const float v6 = w1.z, v7 = w1.w, v8 = w2.x, v9 = w2.y;
                    const float v10 = w2.z, v11 = w2.w, v12 = w3.x, v13 = w3.y;
                    const float v14 = w3.z, v15 = w3.w, v16 = w4.x, v17 = w4.y;
                    const int P = fy * 5;
                    s[0][P+0] = fmaf(v2,  q.x, s[0][P+0]);
                    s[1][P+0] = fmaf(v3,  q.y, s[1][P+0]);
                    s[2][P+0] = fmaf(v4,  q.z, s[2][P+0]);
                    s[3][P+0] = fmaf(v5,  q.w, s[3][P+0]);
                    s[0][P+1] = fmaf(v5,  q.x, s[0][P+1]);
                    s[1][P+1] = fmaf(v6,  q.y, s[1][P+1]);
                    s[2][P+1] = fmaf(v7,  q.z, s[2][P+1]);
                    s[3][P+1] = fmaf(v8,  q.w, s[3][P+1]);
                    s[0][P+2] = fmaf(v8,  q.x, s[0][P+2]);
                    s[1][P+2] = fmaf(v9,  q.y, s[1][P+2]);
                    s[2][P+2] = fmaf(v10, q.z, s[2][P+2]);
                    s[3][P+2] = fmaf(v11, q.w, s[3][P+2]);
                    s[0][P+3] = fmaf(v11, q.x, s[0][P+3]);
                    s[1][P+3] = fmaf(v12, q.y, s[1][P+3]);
                    s[2][P+3] = fmaf(v13, q.z, s[2][P+3]);
                    s[3][P+3] = fmaf(v14, q.w, s[3][P+3]);
                    s[0][P+4] = fmaf(v14, q.x, s[0][P+4]);
                    s[1][P+4] = fmaf(v15, q.y, s[1][P+4]);
                    s[2][P+4] = fmaf(v16, q.z, s[2][P+4]);
                    s[3][P+4] = fmaf(v17, q.w, s[3][P+4]);
                }
            }
            __syncthreads();     // drains this period's prefetch
            qc0 = qn0; qc1 = qn1;
        }
    }

    // ---------------- phase 2 prologue: V ch0/1 in flight under softmax ------
    loadg(Vb, 0);

    // ---------------- softmax over the 25 taps ----------------
#pragma unroll
    for (int a = 0; a < 4; ++a) {
        float m = s[a][0];
#pragma unroll
        for (int p = 1; p < TAPS; ++p) m = fmaxf(m, s[a][p]);
        float sum = 0.f;
#pragma unroll
        for (int p = 0; p < TAPS; ++p) { float e = __expf(s[a][p] - m); s[a][p] = e; sum += e; }
        const float rs = 1.0f / sum;
#pragma unroll
        for (int p = 0; p < TAPS; ++p) s[a][p] *= rs;
    }

    // ---------------- phase 2: out = sum_p att[p] * V_shift[p] ----------------
    {
        writeg(0);                  // waits on the softmax-covered loads
        loadg(Vb, 2);
        __syncthreads();
#pragma unroll 1
        for (int it = 0; it < 16; ++it) {
            if (it < 15) writeg((it + 1) & 1);
            if (it < 14) loadg(Vb, 2 * it + 4);
            const float* lb = lb0 + (it & 1) * BUFW;
#pragma unroll
            for (int cc = 0; cc < 2; ++cc) {
                float a0 = 0.f, a1 = 0.f, a2 = 0.f, a3 = 0.f;
#pragma unroll
                for (int fy = 0; fy < 5; ++fy) {
                    const float* rp = lb + cc * CHW + fy * (3 * LSTR);
                    const f4 w0 = *(const f4*)(rp + 0);
                    const f4 w1 = *(const f4*)(rp + 4);
                    const f4 w2 = *(const f4*)(rp + 8);
                    const f4 w3 = *(const f4*)(rp + 12);
                    const f4 w4 = *(const f4*)(rp + 16);
                    const float v2 = w0.z, v3 = w0.w, v4 = w1.x, v5 = w1.y;
                    const float v6 = w1.z, v7 = w1.w, v8 = w2.x, v9 = w2.y;
                    const float v10 = w2.z, v11 = w2.w, v12 = w3.x, v13 = w3.y;
                    const float v14 = w3.z, v15 = w3.w, v16 = w4.x, v17 = w4.y;
                    const int P = fy * 5;
                    a0 = fmaf(v2,  s[0][P+0], a0);
                    a1 = fmaf(v3,  s[1][P+0], a1);
                    a2 = fmaf(v4,  s[2][P+0], a2);
                    a3 = fmaf(v5,  s[3][P+0], a3);
                    a0 = fmaf(v5,  s[0][P+1], a0);
                    a1 = fmaf(v6,  s[1][P+1], a1);
                    a2 = fmaf(v7,  s[2][P+1], a2);
                    a3 = fmaf(v8,  s[3][P+1], a3);
                    a0 = fmaf(v8,  s[0][P+2], a0);
                    a1 = fmaf(v9,  s[1][P+2], a1);
                    a2 = fmaf(v10, s[2][P+2], a2);
                    a3 = fmaf(v11, s[3][P+2], a3);
                    a0 = fmaf(v11, s[0][P+3], a0);
                    a1 = fmaf(v12, s[1][P+3], a1);
                    a2 = fmaf(v13, s[2][P+3], a2);
                    a3 = fmaf(v14, s[3][P+3], a3);
                    a0 = fmaf(v14, s[0][P+4], a0);
                    a1 = fmaf(v15, s[1][P+4], a1);
                    a2 = fmaf(v16, s[2][P+4], a2);
                    a3 = fmaf(v17, s[3][P+4], a3);
                }
                *(f4*)(Ob + (size_t)(2 * it + cc) * plane + qoff) =
                    make_float4(a0, a1, a2, a3);
            }
            if (it < 15) __syncthreads();
        }
    }
}

extern "C" void kernel_launch(void* const* d_in, const int* in_sizes, int n_in,
                              void* d_out, int out_size, void* d_ws, size_t ws_size,
                              hipStream_t stream) {
    const float* V = (const float*)d_in[0];
    const float* K = (const float*)d_in[1];
    const float* Q = (const float*)d_in[2];
    // d_in[3] = ksize (5), d_in[4] = dilation (3): fixed by setup_inputs.
    float* O = (float*)d_out;

    const int N = in_sizes[0] / (256 * Hh * Ww);  // = 8
    dim3 grid(Hh / 8, N * 8);
    dim3 block(256);
    infusion_kernel<<<grid, block, 0, stream>>>(V, K, Q, O);
}